// Round 10
// baseline (1822.451 us; speedup 1.0000x reference)
//
#include <hip/hip_runtime.h>
#include <stdint.h>
#include <stddef.h>

// ---------------------------------------------------------------------------
// PCgraph: T=32 steps of
//   mu = tanh(x) @ w^T ; e = (x-mu)*m ; g = e @ w ;
//   x = x - 0.1*m*(e - (1-tanh(x)^2)*g)
// bf16 MFMA 16x16x32, fp32 accum. x state in d_out (fp32).
// Round 10: BM=128 tile (halves staged bytes: B re-streamed 2x not 4x;
// doubles MFMA per staged KB) + runtime split-K choice. Round 9 established
// the packed-linear staging path runs at the structural ~20 B/cyc/CU; the
// remaining lever is volume and overlap. Z=8 (needs 13.6 MB partials, ws end
// 66,846,720) gives 832 blocks (~3/CU); if ws_size is smaller fall back to
// Z=4 within the proven 60,030,976-byte footprint. GEMM2 Z=8 uses uneven
// k-slices (7,7,7,7,6,6,6,6 of 52 chunks).
// ---------------------------------------------------------------------------

#define N_DIM 4096
#define B_DIM 256
#define T_STEPS 32
#define LR_X 0.1f
#define N0 768                      // first live column (aligned down from 784)
#define N_LIVE 3328                 // 4096 - 768 = 52*64

#define BM 128
#define BN 64
#define BK 64
#define NCH1 64                     // k-chunks in GEMM1 (k over 4096)
#define NCH2 52                     // k-chunks in GEMM2 (k over 3328)

typedef unsigned short ushort_t;
using bf16x8 = __attribute__((ext_vector_type(8))) __bf16;
using f32x4  = __attribute__((ext_vector_type(4))) float;

__device__ __forceinline__ ushort_t f2bf(float f) {
    union { float f; unsigned int u; } v; v.f = f;
    unsigned int r = v.u + 0x7fffu + ((v.u >> 16) & 1u);   // RNE
    return (ushort_t)(r >> 16);
}
__device__ __forceinline__ float bf2f(ushort_t h) {
    union { unsigned int u; float f; } v; v.u = ((unsigned int)h) << 16;
    return v.f;
}

// fragment-order index of element (r, c) inside a 64x64 tile-chunk
__device__ __forceinline__ int pkidx(int r, int c) {
    const int s = ((r >> 4) << 1) | ((c >> 5) & 1);
    return s * 512 + (r & 15) * 8 + (((c >> 3) & 3) << 7) + (c & 7);
}

__device__ __forceinline__ void async_copy16(const ushort_t* g, ushort_t* l) {
    __builtin_amdgcn_global_load_lds(
        (__attribute__((address_space(1))) void*)(g),
        (__attribute__((address_space(3))) void*)(l),
        16, 0, 0);
}

// --- pack w -> w_pk [52 ntile][64 chunk][4096]  (B of GEMM1: rows 768..4095)
//            -> wt_pk [52 ntile][52 chunk][4096] (B of GEMM2: w^T, live range)
__global__ __launch_bounds__(256) void pack_w(const float* __restrict__ w,
                                              ushort_t* __restrict__ wpk,
                                              ushort_t* __restrict__ wtpk) {
    __shared__ float tile[64][68];
    const int tid = threadIdx.x;
    const int bid = blockIdx.x;
    int row0, col0; ushort_t* dst; bool tr;
    if (bid < 52 * 64) {
        tr   = false;
        dst  = wpk + (size_t)bid * 4096;
        row0 = N0 + (bid >> 6) * 64;      // B-row (n) block
        col0 = (bid & 63) * 64;           // k block
    } else {
        const int b2 = bid - 52 * 64;
        tr   = true;
        dst  = wtpk + (size_t)b2 * 4096;
        const int ntile = b2 / 52, chunk = b2 - ntile * 52;
        row0 = N0 + chunk * 64;           // w-row  = k block (live)
        col0 = N0 + ntile * 64;           // w-col  = n block (live)
    }
    const int rr = tid >> 2, c0 = (tid & 3) * 16;
    const float* src = w + (size_t)(row0 + rr) * N_DIM + col0 + c0;
#pragma unroll
    for (int i = 0; i < 16; i += 4)
        *(float4*)&tile[rr][c0 + i] = *(const float4*)(src + i);
    __syncthreads();
    ushort_t loc[16];
#pragma unroll
    for (int i = 0; i < 16; ++i) {
        const int p = tid * 16 + i;
        const int s = p >> 9, e = p & 511;
        const int r = ((s >> 1) << 4) | ((e >> 3) & 15);
        const int c = ((s & 1) << 5) | (((e >> 7) & 3) << 3) | (e & 7);
        loc[i] = f2bf(tr ? tile[c][r] : tile[r][c]);
    }
    *(uint4*)&dst[tid * 16]     = *(uint4*)&loc[0];
    *(uint4*)&dst[tid * 16 + 8] = *(uint4*)&loc[8];
}

// --- init: x -> d_out (row-major) and t_pk [4 mtile][64 chunk][4096] --------
__global__ __launch_bounds__(256) void pack_t_init(const float* __restrict__ xin,
                                                   float* __restrict__ xout,
                                                   ushort_t* __restrict__ tpk) {
    __shared__ float tile[64][68];
    const int tid  = threadIdx.x;
    const int bid  = blockIdx.x;          // mtile*64 + chunk
    const int row0 = (bid >> 6) * 64;
    const int col0 = (bid & 63) * 64;
    const int rr = tid >> 2, c0 = (tid & 3) * 16;
    const size_t sidx = (size_t)(row0 + rr) * N_DIM + col0 + c0;
#pragma unroll
    for (int i = 0; i < 16; i += 4) {
        float4 v = *(const float4*)(xin + sidx + i);
        *(float4*)(xout + sidx + i) = v;
        tile[rr][c0 + i + 0] = tanhf(v.x);
        tile[rr][c0 + i + 1] = tanhf(v.y);
        tile[rr][c0 + i + 2] = tanhf(v.z);
        tile[rr][c0 + i + 3] = tanhf(v.w);
    }
    __syncthreads();
    ushort_t loc[16];
    ushort_t* dst = tpk + (size_t)bid * 4096;
#pragma unroll
    for (int i = 0; i < 16; ++i) {
        const int p = tid * 16 + i;
        const int s = p >> 9, e = p & 511;
        const int r = ((s >> 1) << 4) | ((e >> 3) & 15);
        const int c = ((s & 1) << 5) | (((e >> 7) & 3) << 3) | (e & 7);
        loc[i] = f2bf(tile[r][c]);
    }
    *(uint4*)&dst[tid * 16]     = *(uint4*)&loc[0];
    *(uint4*)&dst[tid * 16 + 8] = *(uint4*)&loc[8];
}

// --- cvt1 (after GEMM1): mu = sum partials; e -> e_pk (packed, GEMM2 A) -----
__global__ void cvt1(const float* __restrict__ xbuf,
                     const ushort_t* __restrict__ part,
                     ushort_t* __restrict__ epk,
                     const int* __restrict__ mask, int nz) {
    const int b  = blockIdx.y;
    const int nl = blockIdx.x * 256 + threadIdx.x;
    const size_t il = (size_t)b * N_LIVE + nl;
    float mu = 0.0f;
    for (int z = 0; z < nz; ++z)
        mu += bf2f(part[(size_t)z * (B_DIM * N_LIVE) + il]);
    const float x = xbuf[(size_t)b * N_DIM + N0 + nl];
    const float e = (x - mu) * (float)mask[N0 + nl];
    epk[((size_t)((b >> 6) * NCH2 + (nl >> 6))) * 4096 + pkidx(b & 63, nl & 63)]
        = f2bf(e);
}

// --- cvt2 (after GEMM2): g = sum partials; x update; refresh t_pk -----------
__global__ void cvt2(float* __restrict__ xbuf,
                     const ushort_t* __restrict__ part,
                     const ushort_t* __restrict__ epk,
                     ushort_t* __restrict__ tpk,
                     const int* __restrict__ mask, int nz) {
    const int b  = blockIdx.y;
    const int nl = blockIdx.x * 256 + threadIdx.x;
    const size_t ix = (size_t)b * N_DIM + N0 + nl;
    float g = 0.0f;
    for (int z = 0; z < nz; ++z)
        g += bf2f(part[(size_t)z * (B_DIM * N_LIVE) + (size_t)b * N_LIVE + nl]);
    const float x  = xbuf[ix];
    const float th = tanhf(x);
    const float e  = bf2f(epk[((size_t)((b >> 6) * NCH2 + (nl >> 6))) * 4096
                              + pkidx(b & 63, nl & 63)]);
    const float m  = (float)mask[N0 + nl];
    const float xn = x - LR_X * m * (e - (1.0f - th * th) * g);
    xbuf[ix] = xn;
    const int k = N0 + nl;
    tpk[((size_t)((b >> 6) * NCH1 + (k >> 6))) * 4096 + pkidx(b & 63, k & 63)]
        = f2bf(tanhf(xn));
}

// --- split-K GEMM, BM=128: A = two packed mtiles, B = one packed ntile ------
// grid (52, 2, Z); z-slice = [kstart, kstart+kcount) chunks, uneven ok.
template <int NCH>
__global__ __launch_bounds__(256) void gemm_split(
    const ushort_t* __restrict__ Apk,
    const ushort_t* __restrict__ Bpk,
    ushort_t* __restrict__ part, int Z) {
    __shared__ __align__(16) ushort_t As[2][BM * BK];   // 2 x 16 KB
    __shared__ __align__(16) ushort_t Bs[2][BN * BK];   // 2 x 8 KB

    const int tid    = threadIdx.x;
    const int lane   = tid & 63;
    const int wid    = tid >> 6;       // 0..3
    const int wave_m = wid >> 1;       // 0..1  (row half of 128)
    const int wave_n = wid & 1;        // 0..1
    const int ntile  = blockIdx.x;
    const int mtile2 = blockIdx.y;     // 0..1, covers mtiles {2y, 2y+1}
    const int z      = blockIdx.z;

    const int per = NCH / Z, rem = NCH % Z;
    const int kcount = per + (z < rem ? 1 : 0);
    const int kstart = z * per + (z < rem ? z : rem);
    ushort_t* pout = part + (size_t)z * (B_DIM * N_LIVE);

    const int l15  = lane & 15;
    const int quad = lane >> 4;        // 0..3

    const ushort_t* Ab0 = Apk + ((size_t)(mtile2 * 2) * NCH + kstart) * 4096;
    const ushort_t* Ab1 = Ab0 + (size_t)NCH * 4096;
    const ushort_t* Bb  = Bpk + ((size_t)ntile * NCH + kstart) * 4096;

    auto stage = [&](int buf, int kt) {
        const size_t co = (size_t)kt * 4096;
#pragma unroll
        for (int u = 0; u < 4; ++u) {                   // A: 16 sub-tiles
            const int s   = wid * 4 + u;                // 0..15
            const int off = (s & 7) * 512 + lane * 8;
            const ushort_t* src = (s < 8 ? Ab0 : Ab1) + co + off;
            async_copy16(src, &As[buf][s * 512 + lane * 8]);
        }
#pragma unroll
        for (int u = 0; u < 2; ++u) {                   // B: 8 sub-tiles
            const int off = (wid * 2 + u) * 512 + lane * 8;
            async_copy16(Bb + co + off, &Bs[buf][off]);
        }
    };

    f32x4 acc[4][2] = {};

    auto compute = [&](int buf) {
#pragma unroll
        for (int ks = 0; ks < 2; ++ks) {
            bf16x8 a[4], b[2];
#pragma unroll
            for (int i = 0; i < 4; ++i)
                a[i] = *(const bf16x8*)(
                    &As[buf][wave_m * 4096 + (i * 2 + ks) * 512 + lane * 8]);
#pragma unroll
            for (int j = 0; j < 2; ++j)
                b[j] = *(const bf16x8*)(
                    &Bs[buf][((wave_n * 2 + j) * 2 + ks) * 512 + lane * 8]);
#pragma unroll
            for (int i = 0; i < 4; ++i)
#pragma unroll
                for (int j = 0; j < 2; ++j)
                    acc[i][j] = __builtin_amdgcn_mfma_f32_16x16x32_bf16(
                        a[i], b[j], acc[i][j], 0, 0, 0);
        }
    };

    stage(0, 0);
    __syncthreads();
    for (int kt = 0; kt < kcount; ++kt) {
        if (kt + 1 < kcount) stage((kt + 1) & 1, kt + 1);
        compute(kt & 1);
        __syncthreads();
    }

    // Epilogue: bf16 partial stores. C/D: col = lane&15, row = quad*4+reg
#pragma unroll
    for (int j = 0; j < 2; ++j) {
        const int nl = ntile * BN + wave_n * 32 + j * 16 + l15;
#pragma unroll
        for (int i = 0; i < 4; ++i) {
#pragma unroll
            for (int r = 0; r < 4; ++r) {
                const int m = mtile2 * 128 + wave_m * 64 + i * 16 + quad * 4 + r;
                pout[(size_t)m * N_LIVE + nl] = f2bf(acc[i][j][r]);
            }
        }
    }
}

extern "C" void kernel_launch(void* const* d_in, const int* in_sizes, int n_in,
                              void* d_out, int out_size, void* d_ws, size_t ws_size,
                              hipStream_t stream) {
    const float* x_in  = (const float*)d_in[0];
    const float* w_in  = (const float*)d_in[1];
    const int*   mask  = (const int*)d_in[2];
    float*       xbuf  = (float*)d_out;          // state lives in d_out

    uint8_t* ws = (uint8_t*)d_ws;
    // base layout (end @ 60,030,976 proven safe; Z=8 needs end @ 66,846,720):
    ushort_t* w_pk  = (ushort_t*)(ws);                   // 52*64*4096*2 = 27,262,976
    ushort_t* wt_pk = (ushort_t*)(ws + 27262976);        // 52*52*4096*2 = 22,151,168
    ushort_t* t_pk  = (ushort_t*)(ws + 49414144);        //  4*64*4096*2 =  2,097,152
    ushort_t* e_pk  = (ushort_t*)(ws + 51511296);        //  4*52*4096*2 =  1,703,936
    ushort_t* part  = (ushort_t*)(ws + 53215232);        // Z*256*3328*2

    // Z=8 needs 53,215,232 + 8*1,703,936 = 66,846,720 bytes of ws.
    const int Z = (ws_size >= (size_t)66846720) ? 8 : 4;

    pack_w<<<dim3(52 * 64 + 52 * 52), 256, 0, stream>>>(w_in, w_pk, wt_pk);
    pack_t_init<<<dim3(4 * 64), 256, 0, stream>>>(x_in, xbuf, t_pk);

    const dim3 ggrid(N_LIVE / BN, B_DIM / BM, Z);
    const dim3 cgrid(N_LIVE / 256, B_DIM);
    for (int t = 0; t < T_STEPS; ++t) {
        // GEMM1: part[z] = mu partial ; A = t_pk (64 chunks), B = w_pk
        gemm_split<NCH1><<<ggrid, 256, 0, stream>>>(t_pk, w_pk, part, Z);
        cvt1<<<cgrid, 256, 0, stream>>>(xbuf, part, e_pk, mask, Z);
        // GEMM2: part[z] = g partial ; A = e_pk (52 chunks), B = wt_pk
        gemm_split<NCH2><<<ggrid, 256, 0, stream>>>(e_pk, wt_pk, part, Z);
        cvt2<<<cgrid, 256, 0, stream>>>(xbuf, part, e_pk, t_pk, mask, Z);
    }
}

// Round 11
// 1640.253 us; speedup vs baseline: 1.1111x; 1.1111x over previous
//
#include <hip/hip_runtime.h>
#include <stdint.h>
#include <stddef.h>

// ---------------------------------------------------------------------------
// PCgraph: T=32 steps of
//   mu = tanh(x) @ w^T ; e = (x-mu)*m ; g = e @ w ;
//   x = x - 0.1*m*(e - (1-tanh(x)^2)*g)
// bf16 MFMA 16x16x32, fp32 accum. x state in d_out (fp32).
// Round 11: BM=128, BK=32 -> 24 KB LDS. Round 10 proved the BM=128 byte
// saving (213->160 MB staged/GEMM1) is real but its 48 KB LDS capped
// co-residency at 3 blocks/CU (<832-block grid) and re-exposed fill latency.
// BK=32 keeps the byte saving AND 6 blocks/CU cap -> all 832 blocks resident,
// ~13 waves/CU (r9's proven hiding). r9 rate analysis: staging runs at
// ~11.4 TB/s aggregate (L3-BW-bound), so bytes are the lever. Half-chunk
// staging stays 1KB-linear (packed sub-tiles are 512-elem units; k-half =
// even/odd sub-tile). Z=8 (proven: ws >= 66,846,720 B held r10's partials).
// ---------------------------------------------------------------------------

#define N_DIM 4096
#define B_DIM 256
#define T_STEPS 32
#define LR_X 0.1f
#define N0 768                      // first live column (aligned down from 784)
#define N_LIVE 3328                 // 4096 - 768 = 52*64

#define BM 128
#define BN 64
#define NCH1 64                     // 64-wide k-chunks in GEMM1 (k over 4096)
#define NCH2 52                     // k-chunks in GEMM2 (k over 3328)

typedef unsigned short ushort_t;
using bf16x8 = __attribute__((ext_vector_type(8))) __bf16;
using f32x4  = __attribute__((ext_vector_type(4))) float;

__device__ __forceinline__ ushort_t f2bf(float f) {
    union { float f; unsigned int u; } v; v.f = f;
    unsigned int r = v.u + 0x7fffu + ((v.u >> 16) & 1u);   // RNE
    return (ushort_t)(r >> 16);
}
__device__ __forceinline__ float bf2f(ushort_t h) {
    union { unsigned int u; float f; } v; v.u = ((unsigned int)h) << 16;
    return v.f;
}

// fragment-order index of element (r, c) inside a 64x64 tile-chunk
__device__ __forceinline__ int pkidx(int r, int c) {
    const int s = ((r >> 4) << 1) | ((c >> 5) & 1);
    return s * 512 + (r & 15) * 8 + (((c >> 3) & 3) << 7) + (c & 7);
}

__device__ __forceinline__ void async_copy16(const ushort_t* g, ushort_t* l) {
    __builtin_amdgcn_global_load_lds(
        (__attribute__((address_space(1))) void*)(g),
        (__attribute__((address_space(3))) void*)(l),
        16, 0, 0);
}

// --- pack w -> w_pk [52 ntile][64 chunk][4096]  (B of GEMM1: rows 768..4095)
//            -> wt_pk [52 ntile][52 chunk][4096] (B of GEMM2: w^T, live range)
__global__ __launch_bounds__(256) void pack_w(const float* __restrict__ w,
                                              ushort_t* __restrict__ wpk,
                                              ushort_t* __restrict__ wtpk) {
    __shared__ float tile[64][68];
    const int tid = threadIdx.x;
    const int bid = blockIdx.x;
    int row0, col0; ushort_t* dst; bool tr;
    if (bid < 52 * 64) {
        tr   = false;
        dst  = wpk + (size_t)bid * 4096;
        row0 = N0 + (bid >> 6) * 64;      // B-row (n) block
        col0 = (bid & 63) * 64;           // k block
    } else {
        const int b2 = bid - 52 * 64;
        tr   = true;
        dst  = wtpk + (size_t)b2 * 4096;
        const int ntile = b2 / 52, chunk = b2 - ntile * 52;
        row0 = N0 + chunk * 64;           // w-row  = k block (live)
        col0 = N0 + ntile * 64;           // w-col  = n block (live)
    }
    const int rr = tid >> 2, c0 = (tid & 3) * 16;
    const float* src = w + (size_t)(row0 + rr) * N_DIM + col0 + c0;
#pragma unroll
    for (int i = 0; i < 16; i += 4)
        *(float4*)&tile[rr][c0 + i] = *(const float4*)(src + i);
    __syncthreads();
    ushort_t loc[16];
#pragma unroll
    for (int i = 0; i < 16; ++i) {
        const int p = tid * 16 + i;
        const int s = p >> 9, e = p & 511;
        const int r = ((s >> 1) << 4) | ((e >> 3) & 15);
        const int c = ((s & 1) << 5) | (((e >> 7) & 3) << 3) | (e & 7);
        loc[i] = f2bf(tr ? tile[c][r] : tile[r][c]);
    }
    *(uint4*)&dst[tid * 16]     = *(uint4*)&loc[0];
    *(uint4*)&dst[tid * 16 + 8] = *(uint4*)&loc[8];
}

// --- init: x -> d_out (row-major) and t_pk [4 mtile][64 chunk][4096] --------
__global__ __launch_bounds__(256) void pack_t_init(const float* __restrict__ xin,
                                                   float* __restrict__ xout,
                                                   ushort_t* __restrict__ tpk) {
    __shared__ float tile[64][68];
    const int tid  = threadIdx.x;
    const int bid  = blockIdx.x;          // mtile*64 + chunk
    const int row0 = (bid >> 6) * 64;
    const int col0 = (bid & 63) * 64;
    const int rr = tid >> 2, c0 = (tid & 3) * 16;
    const size_t sidx = (size_t)(row0 + rr) * N_DIM + col0 + c0;
#pragma unroll
    for (int i = 0; i < 16; i += 4) {
        float4 v = *(const float4*)(xin + sidx + i);
        *(float4*)(xout + sidx + i) = v;
        tile[rr][c0 + i + 0] = tanhf(v.x);
        tile[rr][c0 + i + 1] = tanhf(v.y);
        tile[rr][c0 + i + 2] = tanhf(v.z);
        tile[rr][c0 + i + 3] = tanhf(v.w);
    }
    __syncthreads();
    ushort_t loc[16];
    ushort_t* dst = tpk + (size_t)bid * 4096;
#pragma unroll
    for (int i = 0; i < 16; ++i) {
        const int p = tid * 16 + i;
        const int s = p >> 9, e = p & 511;
        const int r = ((s >> 1) << 4) | ((e >> 3) & 15);
        const int c = ((s & 1) << 5) | (((e >> 7) & 3) << 3) | (e & 7);
        loc[i] = f2bf(tile[r][c]);
    }
    *(uint4*)&dst[tid * 16]     = *(uint4*)&loc[0];
    *(uint4*)&dst[tid * 16 + 8] = *(uint4*)&loc[8];
}

// --- cvt1 (after GEMM1): mu = sum partials; e -> e_pk (packed, GEMM2 A) -----
__global__ void cvt1(const float* __restrict__ xbuf,
                     const ushort_t* __restrict__ part,
                     ushort_t* __restrict__ epk,
                     const int* __restrict__ mask, int nz) {
    const int b  = blockIdx.y;
    const int nl = blockIdx.x * 256 + threadIdx.x;
    const size_t il = (size_t)b * N_LIVE + nl;
    float mu = 0.0f;
    for (int z = 0; z < nz; ++z)
        mu += bf2f(part[(size_t)z * (B_DIM * N_LIVE) + il]);
    const float x = xbuf[(size_t)b * N_DIM + N0 + nl];
    const float e = (x - mu) * (float)mask[N0 + nl];
    epk[((size_t)((b >> 6) * NCH2 + (nl >> 6))) * 4096 + pkidx(b & 63, nl & 63)]
        = f2bf(e);
}

// --- cvt2 (after GEMM2): g = sum partials; x update; refresh t_pk -----------
__global__ void cvt2(float* __restrict__ xbuf,
                     const ushort_t* __restrict__ part,
                     const ushort_t* __restrict__ epk,
                     ushort_t* __restrict__ tpk,
                     const int* __restrict__ mask, int nz) {
    const int b  = blockIdx.y;
    const int nl = blockIdx.x * 256 + threadIdx.x;
    const size_t ix = (size_t)b * N_DIM + N0 + nl;
    float g = 0.0f;
    for (int z = 0; z < nz; ++z)
        g += bf2f(part[(size_t)z * (B_DIM * N_LIVE) + (size_t)b * N_LIVE + nl]);
    const float x  = xbuf[ix];
    const float th = tanhf(x);
    const float e  = bf2f(epk[((size_t)((b >> 6) * NCH2 + (nl >> 6))) * 4096
                              + pkidx(b & 63, nl & 63)]);
    const float m  = (float)mask[N0 + nl];
    const float xn = x - LR_X * m * (e - (1.0f - th * th) * g);
    xbuf[ix] = xn;
    const int k = N0 + nl;
    tpk[((size_t)((b >> 6) * NCH1 + (k >> 6))) * 4096 + pkidx(b & 63, k & 63)]
        = f2bf(tanhf(xn));
}

// --- split-K GEMM, BM=128 / BK=32 (half-chunk iters), 24 KB LDS -------------
// grid (52, 2, Z). K measured in 32-wide "halves": NH = 2*NCH; NH % Z == 0
// for Z in {4, 8} on both GEMMs (128, 104 halves).
// A sub-tile st = p*4 + g2 (p = mtile half, g2 = 16-row group): 8 x 1KB.
// B sub-tile g2: 4 x 1KB. All staging instructions 1KB lane-linear.
template <int NCH>
__global__ __launch_bounds__(256) void gemm_split(
    const ushort_t* __restrict__ Apk,
    const ushort_t* __restrict__ Bpk,
    ushort_t* __restrict__ part, int Z) {
    __shared__ __align__(16) ushort_t As[2][8 * 512];   // 2 x 8 KB
    __shared__ __align__(16) ushort_t Bs[2][4 * 512];   // 2 x 4 KB

    const int tid    = threadIdx.x;
    const int lane   = tid & 63;
    const int wid    = tid >> 6;       // 0..3
    const int wave_m = wid >> 1;       // 0..1  (64-row half of 128)
    const int wave_n = wid & 1;        // 0..1
    const int ntile  = blockIdx.x;
    const int mtile2 = blockIdx.y;     // covers mtiles {2y, 2y+1}
    const int z      = blockIdx.z;

    const int NH  = 2 * NCH;
    const int per = NH / Z;            // 16 / 13 (Z=8), 32 / 26 (Z=4)
    const int h0  = z * per;
    ushort_t* pout = part + (size_t)z * (B_DIM * N_LIVE);

    const int l15  = lane & 15;
    const int quad = lane >> 4;        // 0..3

    const ushort_t* Ab0 = Apk + (size_t)(mtile2 * 2) * NCH * 4096;
    const ushort_t* Ab1 = Ab0 + (size_t)NCH * 4096;
    const ushort_t* Bb  = Bpk + (size_t)ntile * NCH * 4096;

    auto stage = [&](int buf, int h) {
        const size_t co = (size_t)(h >> 1) * 4096;   // chunk offset
        const int hh = h & 1;                        // k-half within chunk
#pragma unroll
        for (int u = 0; u < 2; ++u) {                // A: 2 sub-tiles/wave
            const int st = wid * 2 + u;              // 0..7 = p*4 + g2
            const int p  = st >> 2, g2 = st & 3;
            const ushort_t* src =
                (p ? Ab1 : Ab0) + co + (g2 * 2 + hh) * 512 + lane * 8;
            async_copy16(src, &As[buf][st * 512 + lane * 8]);
        }
        // B: 1 sub-tile/wave (g2 = wid)
        async_copy16(Bb + co + (wid * 2 + hh) * 512 + lane * 8,
                     &Bs[buf][wid * 512 + lane * 8]);
    };

    f32x4 acc[4][2] = {};

    auto compute = [&](int buf) {
        bf16x8 a[4], b[2];
#pragma unroll
        for (int i = 0; i < 4; ++i)
            a[i] = *(const bf16x8*)(&As[buf][(wave_m * 4 + i) * 512 + lane * 8]);
#pragma unroll
        for (int j = 0; j < 2; ++j)
            b[j] = *(const bf16x8*)(&Bs[buf][(wave_n * 2 + j) * 512 + lane * 8]);
#pragma unroll
        for (int i = 0; i < 4; ++i)
#pragma unroll
            for (int j = 0; j < 2; ++j)
                acc[i][j] = __builtin_amdgcn_mfma_f32_16x16x32_bf16(
                    a[i], b[j], acc[i][j], 0, 0, 0);
    };

    stage(0, h0);
    __syncthreads();
    for (int it = 0; it < per; ++it) {
        if (it + 1 < per) stage((it + 1) & 1, h0 + it + 1);
        compute(it & 1);
        __syncthreads();
    }

    // Epilogue: bf16 partial stores. C/D: col = lane&15, row = quad*4+reg
#pragma unroll
    for (int j = 0; j < 2; ++j) {
        const int nl = ntile * BN + wave_n * 32 + j * 16 + l15;
#pragma unroll
        for (int i = 0; i < 4; ++i) {
#pragma unroll
            for (int r = 0; r < 4; ++r) {
                const int m = mtile2 * 128 + wave_m * 64 + i * 16 + quad * 4 + r;
                pout[(size_t)m * N_LIVE + nl] = f2bf(acc[i][j][r]);
            }
        }
    }
}

extern "C" void kernel_launch(void* const* d_in, const int* in_sizes, int n_in,
                              void* d_out, int out_size, void* d_ws, size_t ws_size,
                              hipStream_t stream) {
    const float* x_in  = (const float*)d_in[0];
    const float* w_in  = (const float*)d_in[1];
    const int*   mask  = (const int*)d_in[2];
    float*       xbuf  = (float*)d_out;          // state lives in d_out

    uint8_t* ws = (uint8_t*)d_ws;
    ushort_t* w_pk  = (ushort_t*)(ws);                   // 52*64*4096*2 = 27,262,976
    ushort_t* wt_pk = (ushort_t*)(ws + 27262976);        // 52*52*4096*2 = 22,151,168
    ushort_t* t_pk  = (ushort_t*)(ws + 49414144);        //  4*64*4096*2 =  2,097,152
    ushort_t* e_pk  = (ushort_t*)(ws + 51511296);        //  4*52*4096*2 =  1,703,936
    ushort_t* part  = (ushort_t*)(ws + 53215232);        // Z*256*3328*2

    // Z=8 end @ 66,846,720 bytes (proven in-bounds by round 10's Z=8 run).
    const int Z = (ws_size >= (size_t)66846720) ? 8 : 4;

    pack_w<<<dim3(52 * 64 + 52 * 52), 256, 0, stream>>>(w_in, w_pk, wt_pk);
    pack_t_init<<<dim3(4 * 64), 256, 0, stream>>>(x_in, xbuf, t_pk);

    const dim3 ggrid(N_LIVE / BN, B_DIM / BM, Z);
    const dim3 cgrid(N_LIVE / 256, B_DIM);
    for (int t = 0; t < T_STEPS; ++t) {
        // GEMM1: part[z] = mu partial ; A = t_pk (128 halves), B = w_pk
        gemm_split<NCH1><<<ggrid, 256, 0, stream>>>(t_pk, w_pk, part, Z);
        cvt1<<<cgrid, 256, 0, stream>>>(xbuf, part, e_pk, mask, Z);
        // GEMM2: part[z] = g partial ; A = e_pk (104 halves), B = wt_pk
        gemm_split<NCH2><<<ggrid, 256, 0, stream>>>(e_pk, wt_pk, part, Z);
        cvt2<<<cgrid, 256, 0, stream>>>(xbuf, part, e_pk, t_pk, mask, Z);
    }
}